// Round 16
// baseline (143.659 us; speedup 1.0000x reference)
//
#include <hip/hip_runtime.h>
#include <hip/hip_bf16.h>

#define B_   2
#define T_   2048
#define HID_ 1024
#define NH_  16
#define HD_  64
#define K_   1024
#define M_   (B_*T_)

typedef __attribute__((ext_vector_type(8)))  short bf16x8;
typedef __attribute__((ext_vector_type(4)))  float f32x4;
typedef __attribute__((ext_vector_type(16))) float f32x16;
typedef __attribute__((ext_vector_type(4)))  unsigned int u32x4;
typedef __attribute__((ext_vector_type(2)))  unsigned int u32x2;

#define LOG2E 1.44269504088896340736f

__device__ inline unsigned short f2bf(float f) {
    __hip_bfloat16 h = __float2bfloat16(f);
    return __builtin_bit_cast(unsigned short, h);
}
__device__ inline unsigned int pk2(float a, float b) {
    return (unsigned int)f2bf(a) | ((unsigned int)f2bf(b) << 16);
}
// truncation pack: (a>>16) | (b & 0xffff0000) in ONE v_perm_b32
__device__ inline unsigned int pkt(float a, float b) {
    return __builtin_amdgcn_perm(__builtin_bit_cast(unsigned, a),
                                 __builtin_bit_cast(unsigned, b), 0x03020706u);
}
__device__ inline bf16x8 cvt8(float4 a, float4 b) {
    bf16x8 r;
    r[0]=(short)f2bf(a.x); r[1]=(short)f2bf(a.y); r[2]=(short)f2bf(a.z); r[3]=(short)f2bf(a.w);
    r[4]=(short)f2bf(b.x); r[5]=(short)f2bf(b.y); r[6]=(short)f2bf(b.z); r[7]=(short)f2bf(b.w);
    return r;
}

// ---------------- fp32 -> bf16 cast, single launch (x + 4 weights) ----------------
__global__ __launch_bounds__(256)
void cast_all(const float* __restrict__ x,
              const float* __restrict__ W0, const float* __restrict__ W1,
              const float* __restrict__ W2, const float* __restrict__ W3,
              unsigned short* __restrict__ xo,
              unsigned short* __restrict__ o0, unsigned short* __restrict__ o1,
              unsigned short* __restrict__ o2, unsigned short* __restrict__ o3) {
    const int blk = blockIdx.x;
    const float* in;
    unsigned short* out;
    int i;
    if (blk < 2048) {
        in = x; out = xo; i = blk * 256 + threadIdx.x;
    } else {
        const int wb = blk - 2048, sec = wb >> 9;
        in  = (sec == 0) ? W0 : (sec == 1) ? W1 : (sec == 2) ? W2 : W3;
        out = (sec == 0) ? o0 : (sec == 1) ? o1 : (sec == 2) ? o2 : o3;
        i = (wb & 511) * 256 + threadIdx.x;
    }
    float4 a = ((const float4*)in)[2*i], b = ((const float4*)in)[2*i + 1];
    ((bf16x8*)out)[i] = cvt8(a, b);
}

// ---------------- bf16 GEMM-NT (proven; kappa-permuted V epilogue) ----------------
template<int TYPE>
__global__ __launch_bounds__(256)
void gemm_k(const unsigned short* __restrict__ A, const unsigned short* __restrict__ W0,
            const unsigned short* __restrict__ W1, const unsigned short* __restrict__ W2,
            const float* __restrict__ cs, const float* __restrict__ sn,
            unsigned short* __restrict__ qb, unsigned short* __restrict__ kb,
            unsigned short* __restrict__ vtb, float* __restrict__ fout) {
    __shared__ unsigned short As[128*64];
    __shared__ unsigned short Bs[128*64];
    const int tid = threadIdx.x;
    const int w = tid >> 6, lane = tid & 63;
    const int u = lane >> 4, c = lane & 15;
    const int bm = blockIdx.x * 128, bn = blockIdx.y * 128;
    const int wm = (w & 1) * 64, wn = (w >> 1) * 64;
    const int srow = tid >> 3, scol = (tid & 7) << 3;

    const unsigned short* Wsec;
    int wrowbase;
    if constexpr (TYPE == 0) {
        const int sec = bn >> 10;
        Wsec = (sec == 0) ? W0 : ((sec == 1) ? W1 : W2);
        wrowbase = bn & 1023;
    } else {
        Wsec = W0;
        wrowbase = bn;
    }
    const unsigned short* Wp = Wsec + (size_t)(wrowbase + srow) * K_ + scol;
    const unsigned short* Ap = A + (size_t)(bm + srow) * K_ + scol;

    f32x4 acc[4][4] = {};
    bf16x8 ra[4], rb[4];

    auto loadin = [&](int k0) {
        #pragma unroll
        for (int i = 0; i < 4; ++i) {
            ra[i] = *(const bf16x8*)(Ap + (size_t)i * 32 * K_ + k0);
            rb[i] = *(const bf16x8*)(Wp + (size_t)i * 32 * K_ + k0);
        }
    };
    loadin(0);

    for (int k0 = 0; k0 < K_; k0 += 64) {
        __syncthreads();
        #pragma unroll
        for (int i = 0; i < 4; ++i) {
            const int row = i * 32 + srow;
            const int sc = (scol * 2) ^ ((row & 7) << 4);
            *(bf16x8*)((char*)As + row * 128 + sc) = ra[i];
            *(bf16x8*)((char*)Bs + row * 128 + sc) = rb[i];
        }
        __syncthreads();
        if (k0 < K_ - 64) loadin(k0 + 64);
        #pragma unroll
        for (int kk = 0; kk < 2; ++kk) {
            bf16x8 af[4], bfr[4];
            #pragma unroll
            for (int mi = 0; mi < 4; ++mi) {
                const int row = wm + mi * 16 + c;
                const int sc = (kk * 64 + u * 16) ^ ((row & 7) << 4);
                af[mi] = *(const bf16x8*)((char*)As + row * 128 + sc);
            }
            #pragma unroll
            for (int ni = 0; ni < 4; ++ni) {
                const int row = wn + ni * 16 + c;
                const int sc = (kk * 64 + u * 16) ^ ((row & 7) << 4);
                bfr[ni] = *(const bf16x8*)((char*)Bs + row * 128 + sc);
            }
            #pragma unroll
            for (int mi = 0; mi < 4; ++mi)
                #pragma unroll
                for (int ni = 0; ni < 4; ++ni)
                    acc[mi][ni] = __builtin_amdgcn_mfma_f32_16x16x32_bf16(
                        af[mi], bfr[ni], acc[mi][ni], 0, 0, 0);
        }
    }

    if constexpr (TYPE == 1) {
        #pragma unroll
        for (int mi = 0; mi < 4; ++mi)
            #pragma unroll
            for (int ni = 0; ni < 4; ++ni)
                #pragma unroll
                for (int r = 0; r < 4; ++r)
                    fout[(size_t)(bm + wm + 16*mi + 4*u + r) * HID_ + (bn + wn + 16*ni + c)] =
                        acc[mi][ni][r];
    } else {
        const int sec = bn >> 10;
        const int h = ((bn + wn) & 1023) >> 6;
        if (sec == 2) {
            #pragma unroll
            for (int mi = 0; mi < 4; ++mi)
                #pragma unroll
                for (int r = 0; r < 4; ++r) {
                    const int mg = bm + wm + 16*mi + 4*u + r;
                    const int bb = mg >> 11, t = mg & 2047;
                    const int tk = (t & ~12) | ((t & 4) << 1) | ((t & 8) >> 1);  // kappa
                    #pragma unroll
                    for (int ni = 0; ni < 4; ++ni)
                        vtb[((size_t)(bb*16 + h) * 64 + 16*ni + c) * 2048 + tk] =
                            f2bf(acc[mi][ni][r]);
                }
        } else {
            unsigned short* ob = sec ? kb : qb;
            const float qsc = sec ? 1.0f : (0.125f * LOG2E);   // q in log2 domain
            #pragma unroll
            for (int mi = 0; mi < 4; ++mi)
                #pragma unroll
                for (int r = 0; r < 4; ++r) {
                    const int mg = bm + wm + 16*mi + 4*u + r;
                    const int bb = mg >> 11, t = mg & 2047;
                    const size_t base = ((size_t)(bb*16 + h) * 2048 + t) * 64;
                    #pragma unroll
                    for (int ni = 0; ni < 2; ++ni) {
                        const int dlo = 16*ni + c;
                        const float cv = cs[t*64 + dlo], sv = sn[t*64 + dlo];
                        const float Aa = acc[mi][ni][r], Bb = acc[mi][ni+2][r];
                        ob[base + dlo]      = f2bf((Aa*cv - Bb*sv) * qsc);
                        ob[base + dlo + 32] = f2bf((Bb*cv + Aa*sv) * qsc);
                    }
                }
        }
    }
}

// ---------------- attn14: attn12 with V un-buffered -> 3 waves/SIMD ----------------
// Same verified math (2 q-tiles/wave, sigma/kappa PV, defer-max, K depth-1 dbuf).
// V loads issue at process() start and are consumed after QK^T+softmax (~400cy
// of natural cover), freeing 32 VGPR so 3 waves/SIMD fit (launch_bounds cap 170;
// est. live state ~152 — positive headroom, unlike R7's 64-vs-104 spill).
__global__ __launch_bounds__(256, 3)
void attn14(const unsigned short* __restrict__ q, const unsigned short* __restrict__ k,
            const unsigned short* __restrict__ vt, unsigned short* __restrict__ ab) {
    const int raw = blockIdx.x;                          // 1024 blocks
    const int bh     = (raw & 7) + 8 * ((raw >> 3) & 3); // same-bh -> same XCD
    const int qchunk = 31 - (raw >> 5);                  // heavy blocks first
    const int tid = threadIdx.x;
    const int wid = tid >> 6, lane = tid & 63;
    const int h = lane >> 5, c = lane & 31;
    const int b = bh >> 4, hh = bh & 15;
    const int q0 = qchunk * 64;
    const int qgcA = q0 + c, qgcB = q0 + 32 + c;
    const int stAd = 2 * qchunk;                         // tile A diag subtile
    const int NT   = 2 * qchunk + 2;                     // KV subtiles (tile B diag = NT-1)
    const unsigned short* qp = q  + (size_t)bh * (T_*64);
    const unsigned short* kp = k  + (size_t)bh * (T_*64);
    const unsigned short* vp = vt + (size_t)bh * (64*T_);

    const int kloff  = c * 64 + 8 * h;
    const int vloff0 = c * 2048 + 8 * h;
    const int vloff1 = vloff0 + 32 * 2048;

    bf16x8 qfA[4], qfB[4];
    {
        const unsigned short* qrowA = qp + (q0 + c) * 64 + 8 * h;
        const unsigned short* qrowB = qrowA + 32 * 64;
        #pragma unroll
        for (int s = 0; s < 4; ++s) {
            qfA[s] = *(const bf16x8*)(qrowA + s * 16);
            qfB[s] = *(const bf16x8*)(qrowB + s * 16);
        }
    }

    f32x16 OA0 = {}, OA1 = {}, OB0 = {}, OB1 = {};
    float mA = -1e30f, lA = 0.f, mB = -1e30f, lB = 0.f;

    auto loadK = [&](bf16x8 (&kf)[4], int st) {
        const unsigned short* kst = kp + (st << 11);
        #pragma unroll
        for (int s = 0; s < 4; ++s)
            kf[s] = *(const bf16x8*)(kst + kloff + s * 16);
    };

    auto process = [&](const bf16x8 (&kf)[4], int st) {
        const int kvs = st << 5;
        // V loads issue NOW; consumed ~400+ cycles later (after QK^T + softmax)
        const unsigned short* vst = vp + (st << 5);
        bf16x8 vf0 = *(const bf16x8*)(vst + vloff0);
        bf16x8 vf1 = *(const bf16x8*)(vst + vloff0 + 16);
        bf16x8 vf2 = *(const bf16x8*)(vst + vloff1);
        bf16x8 vf3 = *(const bf16x8*)(vst + vloff1 + 16);
        const bool doA = (st <= stAd);                   // uniform
        float pA[16], pB[16];
        float mxA = -1e30f, mxB;
        if (doA) {
            __builtin_amdgcn_s_setprio(1);
            f32x16 sa = {};
            #pragma unroll
            for (int s = 0; s < 4; ++s)
                sa = __builtin_amdgcn_mfma_f32_32x32x16_bf16(kf[s], qfA[s], sa, 0, 0, 0);
            __builtin_amdgcn_s_setprio(0);
            #pragma unroll
            for (int r = 0; r < 16; ++r) pA[r] = sa[r];
            if (st == stAd) {
                #pragma unroll
                for (int r = 0; r < 16; ++r) {
                    const int kk = kvs + (r & 3) + 8 * (r >> 2) + 4 * h;
                    if (kk > qgcA) pA[r] = -1e30f;
                }
            }
            const float a0 = fmaxf(fmaxf(pA[0],  pA[1]),  pA[2]);
            const float a1 = fmaxf(fmaxf(pA[3],  pA[4]),  pA[5]);
            const float a2 = fmaxf(fmaxf(pA[6],  pA[7]),  pA[8]);
            const float a3 = fmaxf(fmaxf(pA[9],  pA[10]), pA[11]);
            const float a4 = fmaxf(fmaxf(pA[12], pA[13]), pA[14]);
            mxA = fmaxf(fmaxf(fmaxf(a0, a1), fmaxf(a2, a3)), fmaxf(a4, pA[15]));
        }
        {
            __builtin_amdgcn_s_setprio(1);
            f32x16 sa = {};
            #pragma unroll
            for (int s = 0; s < 4; ++s)
                sa = __builtin_amdgcn_mfma_f32_32x32x16_bf16(kf[s], qfB[s], sa, 0, 0, 0);
            __builtin_amdgcn_s_setprio(0);
            #pragma unroll
            for (int r = 0; r < 16; ++r) pB[r] = sa[r];
            if (st == NT - 1) {
                #pragma unroll
                for (int r = 0; r < 16; ++r) {
                    const int kk = kvs + (r & 3) + 8 * (r >> 2) + 4 * h;
                    if (kk > qgcB) pB[r] = -1e30f;
                }
            }
            const float a0 = fmaxf(fmaxf(pB[0],  pB[1]),  pB[2]);
            const float a1 = fmaxf(fmaxf(pB[3],  pB[4]),  pB[5]);
            const float a2 = fmaxf(fmaxf(pB[6],  pB[7]),  pB[8]);
            const float a3 = fmaxf(fmaxf(pB[9],  pB[10]), pB[11]);
            const float a4 = fmaxf(fmaxf(pB[12], pB[13]), pB[14]);
            mxB = fmaxf(fmaxf(fmaxf(a0, a1), fmaxf(a2, a3)), fmaxf(a4, pB[15]));
        }
        if (!__all(fmaxf(mxA - mA, mxB - mB) <= 8.0f)) {
            if (doA) {
                const float fx = fmaxf(mxA, __shfl_xor(mxA, 32));
                const float mn = fmaxf(mA, fx);
                const float f = __builtin_amdgcn_exp2f(mA - mn);
                mA = mn; lA *= f;
                #pragma unroll
                for (int r = 0; r < 16; ++r) { OA0[r] *= f; OA1[r] *= f; }
            }
            {
                const float fx = fmaxf(mxB, __shfl_xor(mxB, 32));
                const float mn = fmaxf(mB, fx);
                const float f = __builtin_amdgcn_exp2f(mB - mn);
                mB = mn; lB *= f;
                #pragma unroll
                for (int r = 0; r < 16; ++r) { OB0[r] *= f; OB1[r] *= f; }
            }
        }
        if (doA) {
            float ps = 0.f;
            #pragma unroll
            for (int r = 0; r < 16; ++r) {
                pA[r] = __builtin_amdgcn_exp2f(pA[r] - mA);
                ps += pA[r];
            }
            lA += ps;
            u32x4 B0w = { pkt(pA[0],  pA[1]),  pkt(pA[2],  pA[3]),
                          pkt(pA[4],  pA[5]),  pkt(pA[6],  pA[7])  };
            u32x4 B1w = { pkt(pA[8],  pA[9]),  pkt(pA[10], pA[11]),
                          pkt(pA[12], pA[13]), pkt(pA[14], pA[15]) };
            bf16x8 PB0 = __builtin_bit_cast(bf16x8, B0w);
            bf16x8 PB1 = __builtin_bit_cast(bf16x8, B1w);
            __builtin_amdgcn_s_setprio(1);
            OA0 = __builtin_amdgcn_mfma_f32_32x32x16_bf16(vf0, PB0, OA0, 0, 0, 0);
            OA0 = __builtin_amdgcn_mfma_f32_32x32x16_bf16(vf1, PB1, OA0, 0, 0, 0);
            OA1 = __builtin_amdgcn_mfma_f32_32x32x16_bf16(vf2, PB0, OA1, 0, 0, 0);
            OA1 = __builtin_amdgcn_mfma_f32_32x32x16_bf16(vf3, PB1, OA1, 0, 0, 0);
            __builtin_amdgcn_s_setprio(0);
        }
        {
            float ps = 0.f;
            #pragma unroll
            for (int r = 0; r < 16; ++r) {
                pB[r] = __builtin_amdgcn_exp2f(pB[r] - mB);
                ps += pB[r];
            }
            lB += ps;
            u32x4 B0w = { pkt(pB[0],  pB[1]),  pkt(pB[2],  pB[3]),
                          pkt(pB[4],  pB[5]),  pkt(pB[6],  pB[7])  };
            u32x4 B1w = { pkt(pB[8],  pB[9]),  pkt(pB[10], pB[11]),
                          pkt(pB[12], pB[13]), pkt(pB[14], pB[15]) };
            bf16x8 PB0 = __builtin_bit_cast(bf16x8, B0w);
            bf16x8 PB1 = __builtin_bit_cast(bf16x8, B1w);
            __builtin_amdgcn_s_setprio(1);
            OB0 = __builtin_amdgcn_mfma_f32_32x32x16_bf16(vf0, PB0, OB0, 0, 0, 0);
            OB0 = __builtin_amdgcn_mfma_f32_32x32x16_bf16(vf1, PB1, OB0, 0, 0, 0);
            OB1 = __builtin_amdgcn_mfma_f32_32x32x16_bf16(vf2, PB0, OB1, 0, 0, 0);
            OB1 = __builtin_amdgcn_mfma_f32_32x32x16_bf16(vf3, PB1, OB1, 0, 0, 0);
            __builtin_amdgcn_s_setprio(0);
        }
    };

    bf16x8 kA_[4], kB_[4];
    if (wid < NT) loadK(kA_, wid);
    for (int st = wid; st < NT; st += 8) {
        if (st + 4 < NT) loadK(kB_, st + 4);
        process(kA_, st);
        if (st + 4 >= NT) break;
        if (st + 8 < NT) loadK(kA_, st + 8);
        process(kB_, st + 4);
    }
    lA += __shfl_xor(lA, 32);
    lB += __shfl_xor(lB, 32);

    // ---- merge the 4 wave-partials in LDS (bf16-packed, stride 34 u32) ----
    __shared__ unsigned OSu[4][64 * 34];
    __shared__ float mS[4][64], lS[4][64];
    if (h == 0) {
        mS[wid][c] = mA;      lS[wid][c] = lA;
        mS[wid][32 + c] = mB; lS[wid][32 + c] = lB;
    }
    {
        unsigned* os = &OSu[wid][0];
        const int rbA = c * 34 + 2 * h;
        const int rbB = (32 + c) * 34 + 2 * h;
        #pragma unroll
        for (int j = 0; j < 4; ++j) {
            os[rbA + 4*j]          = pk2(OA0[4*j],   OA0[4*j+1]);
            os[rbA + 4*j + 1]      = pk2(OA0[4*j+2], OA0[4*j+3]);
            os[rbA + 16 + 4*j]     = pk2(OA1[4*j],   OA1[4*j+1]);
            os[rbA + 16 + 4*j + 1] = pk2(OA1[4*j+2], OA1[4*j+3]);
            os[rbB + 4*j]          = pk2(OB0[4*j],   OB0[4*j+1]);
            os[rbB + 4*j + 1]      = pk2(OB0[4*j+2], OB0[4*j+3]);
            os[rbB + 16 + 4*j]     = pk2(OB1[4*j],   OB1[4*j+1]);
            os[rbB + 16 + 4*j + 1] = pk2(OB1[4*j+2], OB1[4*j+3]);
        }
    }
    __syncthreads();

    const int ql = tid & 63, ug = (tid >> 6) * 8;   // 8 u32 = 16 d per thread
    const float M = fmaxf(fmaxf(mS[0][ql], mS[1][ql]), fmaxf(mS[2][ql], mS[3][ql]));
    float acc[16] = {};
    float L = 0.f;
    #pragma unroll
    for (int w2 = 0; w2 < 4; ++w2) {
        const float sc = __builtin_amdgcn_exp2f(mS[w2][ql] - M);
        L += lS[w2][ql] * sc;
        u32x4 pa = *(u32x4*)&OSu[w2][ql * 34 + ug];
        u32x4 pb = *(u32x4*)&OSu[w2][ql * 34 + ug + 4];
        #pragma unroll
        for (int t = 0; t < 4; ++t) {
            acc[2*t]     += __builtin_bit_cast(float, pa[t] << 16) * sc;
            acc[2*t+1]   += __builtin_bit_cast(float, pa[t] & 0xffff0000u) * sc;
            acc[8+2*t]   += __builtin_bit_cast(float, pb[t] << 16) * sc;
            acc[8+2*t+1] += __builtin_bit_cast(float, pb[t] & 0xffff0000u) * sc;
        }
    }
    const float inv = 1.0f / L;
    uint4 ov0, ov1;
    ov0.x = pk2(acc[0]*inv,  acc[1]*inv);
    ov0.y = pk2(acc[2]*inv,  acc[3]*inv);
    ov0.z = pk2(acc[4]*inv,  acc[5]*inv);
    ov0.w = pk2(acc[6]*inv,  acc[7]*inv);
    ov1.x = pk2(acc[8]*inv,  acc[9]*inv);
    ov1.y = pk2(acc[10]*inv, acc[11]*inv);
    ov1.z = pk2(acc[12]*inv, acc[13]*inv);
    ov1.w = pk2(acc[14]*inv, acc[15]*inv);
    unsigned short* orow = ab + ((size_t)(b * T_) + q0 + ql) * HID_ + hh * 64 + ug * 2;
    *(uint4*)orow       = ov0;
    *(uint4*)(orow + 8) = ov1;
}

extern "C" void kernel_launch(void* const* d_in, const int* in_sizes, int n_in,
                              void* d_out, int out_size, void* d_ws, size_t ws_size,
                              hipStream_t stream) {
    const float* x  = (const float*)d_in[0];
    const float* Wq = (const float*)d_in[1];
    const float* Wk = (const float*)d_in[2];
    const float* Wv = (const float*)d_in[3];
    const float* Wo = (const float*)d_in[4];
    const float* cs = (const float*)d_in[5];
    const float* sn = (const float*)d_in[6];
    char* wsb = (char*)d_ws;
    unsigned short* xb  = (unsigned short*)(wsb);                  // 8 MB
    unsigned short* wqb = (unsigned short*)(wsb + (8u  << 20));    // 2 MB each
    unsigned short* wkb = (unsigned short*)(wsb + (10u << 20));
    unsigned short* wvb = (unsigned short*)(wsb + (12u << 20));
    unsigned short* wob = (unsigned short*)(wsb + (14u << 20));
    unsigned short* qb  = (unsigned short*)(wsb + (16u << 20));
    unsigned short* kb  = (unsigned short*)(wsb + (24u << 20));
    unsigned short* vtb = (unsigned short*)(wsb + (32u << 20));
    unsigned short* ab  = (unsigned short*)(wsb + (40u << 20));

    cast_all<<<4096, 256, 0, stream>>>(x, Wq, Wk, Wv, Wo, xb, wqb, wkb, wvb, wob);

    gemm_k<0><<<dim3(M_/128, 3072/128), 256, 0, stream>>>(
        xb, wqb, wkb, wvb, cs, sn, qb, kb, vtb, nullptr);
    attn14<<<1024, 256, 0, stream>>>(qb, kb, vtb, ab);
    gemm_k<1><<<dim3(M_/128, HID_/128), 256, 0, stream>>>(
        ab, wob, nullptr, nullptr, nullptr, nullptr,
        nullptr, nullptr, nullptr, (float*)d_out);
}

// Round 17
// 118.434 us; speedup vs baseline: 1.2130x; 1.2130x over previous
//
#include <hip/hip_runtime.h>
#include <hip/hip_bf16.h>

#define B_   2
#define T_   2048
#define HID_ 1024
#define NH_  16
#define HD_  64
#define K_   1024
#define M_   (B_*T_)

typedef __attribute__((ext_vector_type(8)))  short bf16x8;
typedef __attribute__((ext_vector_type(4)))  float f32x4;
typedef __attribute__((ext_vector_type(16))) float f32x16;
typedef __attribute__((ext_vector_type(4)))  unsigned int u32x4;
typedef __attribute__((ext_vector_type(2)))  unsigned int u32x2;

#define LOG2E 1.44269504088896340736f

__device__ inline unsigned short f2bf(float f) {
    __hip_bfloat16 h = __float2bfloat16(f);
    return __builtin_bit_cast(unsigned short, h);
}
__device__ inline unsigned int pk2(float a, float b) {
    return (unsigned int)f2bf(a) | ((unsigned int)f2bf(b) << 16);
}
// truncation pack: (a>>16) | (b & 0xffff0000) in ONE v_perm_b32
__device__ inline unsigned int pkt(float a, float b) {
    return __builtin_amdgcn_perm(__builtin_bit_cast(unsigned, a),
                                 __builtin_bit_cast(unsigned, b), 0x03020706u);
}
__device__ inline bf16x8 cvt8(float4 a, float4 b) {
    bf16x8 r;
    r[0]=(short)f2bf(a.x); r[1]=(short)f2bf(a.y); r[2]=(short)f2bf(a.z); r[3]=(short)f2bf(a.w);
    r[4]=(short)f2bf(b.x); r[5]=(short)f2bf(b.y); r[6]=(short)f2bf(b.z); r[7]=(short)f2bf(b.w);
    return r;
}

// ---------------- fp32 -> bf16 cast, single launch (x + 4 weights) ----------------
__global__ __launch_bounds__(256)
void cast_all(const float* __restrict__ x,
              const float* __restrict__ W0, const float* __restrict__ W1,
              const float* __restrict__ W2, const float* __restrict__ W3,
              unsigned short* __restrict__ xo,
              unsigned short* __restrict__ o0, unsigned short* __restrict__ o1,
              unsigned short* __restrict__ o2, unsigned short* __restrict__ o3) {
    const int blk = blockIdx.x;
    const float* in;
    unsigned short* out;
    int i;
    if (blk < 2048) {
        in = x; out = xo; i = blk * 256 + threadIdx.x;
    } else {
        const int wb = blk - 2048, sec = wb >> 9;
        in  = (sec == 0) ? W0 : (sec == 1) ? W1 : (sec == 2) ? W2 : W3;
        out = (sec == 0) ? o0 : (sec == 1) ? o1 : (sec == 2) ? o2 : o3;
        i = (wb & 511) * 256 + threadIdx.x;
    }
    float4 a = ((const float4*)in)[2*i], b = ((const float4*)in)[2*i + 1];
    ((bf16x8*)out)[i] = cvt8(a, b);
}

// ---------------- bf16 GEMM-NT (proven; kappa-permuted V epilogue) ----------------
template<int TYPE>
__global__ __launch_bounds__(256)
void gemm_k(const unsigned short* __restrict__ A, const unsigned short* __restrict__ W0,
            const unsigned short* __restrict__ W1, const unsigned short* __restrict__ W2,
            const float* __restrict__ cs, const float* __restrict__ sn,
            unsigned short* __restrict__ qb, unsigned short* __restrict__ kb,
            unsigned short* __restrict__ vtb, float* __restrict__ fout) {
    __shared__ unsigned short As[128*64];
    __shared__ unsigned short Bs[128*64];
    const int tid = threadIdx.x;
    const int w = tid >> 6, lane = tid & 63;
    const int u = lane >> 4, c = lane & 15;
    const int bm = blockIdx.x * 128, bn = blockIdx.y * 128;
    const int wm = (w & 1) * 64, wn = (w >> 1) * 64;
    const int srow = tid >> 3, scol = (tid & 7) << 3;

    const unsigned short* Wsec;
    int wrowbase;
    if constexpr (TYPE == 0) {
        const int sec = bn >> 10;
        Wsec = (sec == 0) ? W0 : ((sec == 1) ? W1 : W2);
        wrowbase = bn & 1023;
    } else {
        Wsec = W0;
        wrowbase = bn;
    }
    const unsigned short* Wp = Wsec + (size_t)(wrowbase + srow) * K_ + scol;
    const unsigned short* Ap = A + (size_t)(bm + srow) * K_ + scol;

    f32x4 acc[4][4] = {};
    bf16x8 ra[4], rb[4];

    auto loadin = [&](int k0) {
        #pragma unroll
        for (int i = 0; i < 4; ++i) {
            ra[i] = *(const bf16x8*)(Ap + (size_t)i * 32 * K_ + k0);
            rb[i] = *(const bf16x8*)(Wp + (size_t)i * 32 * K_ + k0);
        }
    };
    loadin(0);

    for (int k0 = 0; k0 < K_; k0 += 64) {
        __syncthreads();
        #pragma unroll
        for (int i = 0; i < 4; ++i) {
            const int row = i * 32 + srow;
            const int sc = (scol * 2) ^ ((row & 7) << 4);
            *(bf16x8*)((char*)As + row * 128 + sc) = ra[i];
            *(bf16x8*)((char*)Bs + row * 128 + sc) = rb[i];
        }
        __syncthreads();
        if (k0 < K_ - 64) loadin(k0 + 64);
        #pragma unroll
        for (int kk = 0; kk < 2; ++kk) {
            bf16x8 af[4], bfr[4];
            #pragma unroll
            for (int mi = 0; mi < 4; ++mi) {
                const int row = wm + mi * 16 + c;
                const int sc = (kk * 64 + u * 16) ^ ((row & 7) << 4);
                af[mi] = *(const bf16x8*)((char*)As + row * 128 + sc);
            }
            #pragma unroll
            for (int ni = 0; ni < 4; ++ni) {
                const int row = wn + ni * 16 + c;
                const int sc = (kk * 64 + u * 16) ^ ((row & 7) << 4);
                bfr[ni] = *(const bf16x8*)((char*)Bs + row * 128 + sc);
            }
            #pragma unroll
            for (int mi = 0; mi < 4; ++mi)
                #pragma unroll
                for (int ni = 0; ni < 4; ++ni)
                    acc[mi][ni] = __builtin_amdgcn_mfma_f32_16x16x32_bf16(
                        af[mi], bfr[ni], acc[mi][ni], 0, 0, 0);
        }
    }

    if constexpr (TYPE == 1) {
        #pragma unroll
        for (int mi = 0; mi < 4; ++mi)
            #pragma unroll
            for (int ni = 0; ni < 4; ++ni)
                #pragma unroll
                for (int r = 0; r < 4; ++r)
                    fout[(size_t)(bm + wm + 16*mi + 4*u + r) * HID_ + (bn + wn + 16*ni + c)] =
                        acc[mi][ni][r];
    } else {
        const int sec = bn >> 10;
        const int h = ((bn + wn) & 1023) >> 6;
        if (sec == 2) {
            #pragma unroll
            for (int mi = 0; mi < 4; ++mi)
                #pragma unroll
                for (int r = 0; r < 4; ++r) {
                    const int mg = bm + wm + 16*mi + 4*u + r;
                    const int bb = mg >> 11, t = mg & 2047;
                    const int tk = (t & ~12) | ((t & 4) << 1) | ((t & 8) >> 1);  // kappa
                    #pragma unroll
                    for (int ni = 0; ni < 4; ++ni)
                        vtb[((size_t)(bb*16 + h) * 64 + 16*ni + c) * 2048 + tk] =
                            f2bf(acc[mi][ni][r]);
                }
        } else {
            unsigned short* ob = sec ? kb : qb;
            const float qsc = sec ? 1.0f : (0.125f * LOG2E);   // q in log2 domain
            #pragma unroll
            for (int mi = 0; mi < 4; ++mi)
                #pragma unroll
                for (int r = 0; r < 4; ++r) {
                    const int mg = bm + wm + 16*mi + 4*u + r;
                    const int bb = mg >> 11, t = mg & 2047;
                    const size_t base = ((size_t)(bb*16 + h) * 2048 + t) * 64;
                    #pragma unroll
                    for (int ni = 0; ni < 2; ++ni) {
                        const int dlo = 16*ni + c;
                        const float cv = cs[t*64 + dlo], sv = sn[t*64 + dlo];
                        const float Aa = acc[mi][ni][r], Bb = acc[mi][ni+2][r];
                        ob[base + dlo]      = f2bf((Aa*cv - Bb*sv) * qsc);
                        ob[base + dlo + 32] = f2bf((Bb*cv + Aa*sv) * qsc);
                    }
                }
        }
    }
}

// ---------------- attn15: attn12 loop + V-in-process, NO occupancy cap ----------------
// Math identical to attn12/attn14 (both passed). K depth-1 double-buffer (proven),
// V loaded at process() start (consumed after QK^T+softmax ~400cy later). Est.
// register demand ~164; if the UNCONSTRAINED allocator lands <=168 we get
// 3 waves/SIMD for free. R7/R16 lesson: never force it with launch_bounds.
__global__ __launch_bounds__(256)
void attn15(const unsigned short* __restrict__ q, const unsigned short* __restrict__ k,
            const unsigned short* __restrict__ vt, unsigned short* __restrict__ ab) {
    const int raw = blockIdx.x;                          // 1024 blocks
    const int bh     = (raw & 7) + 8 * ((raw >> 3) & 3); // same-bh -> same XCD
    const int qchunk = 31 - (raw >> 5);                  // heavy blocks first
    const int tid = threadIdx.x;
    const int wid = tid >> 6, lane = tid & 63;
    const int h = lane >> 5, c = lane & 31;
    const int b = bh >> 4, hh = bh & 15;
    const int q0 = qchunk * 64;
    const int qgcA = q0 + c, qgcB = q0 + 32 + c;
    const int stAd = 2 * qchunk;                         // tile A diag subtile
    const int NT   = 2 * qchunk + 2;                     // KV subtiles (tile B diag = NT-1)
    const unsigned short* qp = q  + (size_t)bh * (T_*64);
    const unsigned short* kp = k  + (size_t)bh * (T_*64);
    const unsigned short* vp = vt + (size_t)bh * (64*T_);

    const int kloff  = c * 64 + 8 * h;
    const int vloff0 = c * 2048 + 8 * h;
    const int vloff1 = vloff0 + 32 * 2048;

    bf16x8 qfA[4], qfB[4];
    {
        const unsigned short* qrowA = qp + (q0 + c) * 64 + 8 * h;
        const unsigned short* qrowB = qrowA + 32 * 64;
        #pragma unroll
        for (int s = 0; s < 4; ++s) {
            qfA[s] = *(const bf16x8*)(qrowA + s * 16);
            qfB[s] = *(const bf16x8*)(qrowB + s * 16);
        }
    }

    f32x16 OA0 = {}, OA1 = {}, OB0 = {}, OB1 = {};
    float mA = -1e30f, lA = 0.f, mB = -1e30f, lB = 0.f;

    auto loadK = [&](bf16x8 (&kf)[4], int st) {
        const unsigned short* kst = kp + (st << 11);
        #pragma unroll
        for (int s = 0; s < 4; ++s)
            kf[s] = *(const bf16x8*)(kst + kloff + s * 16);
    };

    auto process = [&](const bf16x8 (&kf)[4], int st) {
        const int kvs = st << 5;
        // V loads issue NOW; consumed after QK^T + softmax (~400cy of cover)
        const unsigned short* vst = vp + (st << 5);
        bf16x8 vf0 = *(const bf16x8*)(vst + vloff0);
        bf16x8 vf1 = *(const bf16x8*)(vst + vloff0 + 16);
        bf16x8 vf2 = *(const bf16x8*)(vst + vloff1);
        bf16x8 vf3 = *(const bf16x8*)(vst + vloff1 + 16);
        const bool doA = (st <= stAd);                   // uniform
        float pA[16], pB[16];
        float mxA = -1e30f, mxB;
        if (doA) {
            __builtin_amdgcn_s_setprio(1);
            f32x16 sa = {};
            #pragma unroll
            for (int s = 0; s < 4; ++s)
                sa = __builtin_amdgcn_mfma_f32_32x32x16_bf16(kf[s], qfA[s], sa, 0, 0, 0);
            __builtin_amdgcn_s_setprio(0);
            #pragma unroll
            for (int r = 0; r < 16; ++r) pA[r] = sa[r];
            if (st == stAd) {
                #pragma unroll
                for (int r = 0; r < 16; ++r) {
                    const int kk = kvs + (r & 3) + 8 * (r >> 2) + 4 * h;
                    if (kk > qgcA) pA[r] = -1e30f;
                }
            }
            const float a0 = fmaxf(fmaxf(pA[0],  pA[1]),  pA[2]);
            const float a1 = fmaxf(fmaxf(pA[3],  pA[4]),  pA[5]);
            const float a2 = fmaxf(fmaxf(pA[6],  pA[7]),  pA[8]);
            const float a3 = fmaxf(fmaxf(pA[9],  pA[10]), pA[11]);
            const float a4 = fmaxf(fmaxf(pA[12], pA[13]), pA[14]);
            mxA = fmaxf(fmaxf(fmaxf(a0, a1), fmaxf(a2, a3)), fmaxf(a4, pA[15]));
        }
        {
            __builtin_amdgcn_s_setprio(1);
            f32x16 sa = {};
            #pragma unroll
            for (int s = 0; s < 4; ++s)
                sa = __builtin_amdgcn_mfma_f32_32x32x16_bf16(kf[s], qfB[s], sa, 0, 0, 0);
            __builtin_amdgcn_s_setprio(0);
            #pragma unroll
            for (int r = 0; r < 16; ++r) pB[r] = sa[r];
            if (st == NT - 1) {
                #pragma unroll
                for (int r = 0; r < 16; ++r) {
                    const int kk = kvs + (r & 3) + 8 * (r >> 2) + 4 * h;
                    if (kk > qgcB) pB[r] = -1e30f;
                }
            }
            const float a0 = fmaxf(fmaxf(pB[0],  pB[1]),  pB[2]);
            const float a1 = fmaxf(fmaxf(pB[3],  pB[4]),  pB[5]);
            const float a2 = fmaxf(fmaxf(pB[6],  pB[7]),  pB[8]);
            const float a3 = fmaxf(fmaxf(pB[9],  pB[10]), pB[11]);
            const float a4 = fmaxf(fmaxf(pB[12], pB[13]), pB[14]);
            mxB = fmaxf(fmaxf(fmaxf(a0, a1), fmaxf(a2, a3)), fmaxf(a4, pB[15]));
        }
        if (!__all(fmaxf(mxA - mA, mxB - mB) <= 8.0f)) {
            if (doA) {
                const float fx = fmaxf(mxA, __shfl_xor(mxA, 32));
                const float mn = fmaxf(mA, fx);
                const float f = __builtin_amdgcn_exp2f(mA - mn);
                mA = mn; lA *= f;
                #pragma unroll
                for (int r = 0; r < 16; ++r) { OA0[r] *= f; OA1[r] *= f; }
            }
            {
                const float fx = fmaxf(mxB, __shfl_xor(mxB, 32));
                const float mn = fmaxf(mB, fx);
                const float f = __builtin_amdgcn_exp2f(mB - mn);
                mB = mn; lB *= f;
                #pragma unroll
                for (int r = 0; r < 16; ++r) { OB0[r] *= f; OB1[r] *= f; }
            }
        }
        if (doA) {
            float ps = 0.f;
            #pragma unroll
            for (int r = 0; r < 16; ++r) {
                pA[r] = __builtin_amdgcn_exp2f(pA[r] - mA);
                ps += pA[r];
            }
            lA += ps;
            u32x4 B0w = { pkt(pA[0],  pA[1]),  pkt(pA[2],  pA[3]),
                          pkt(pA[4],  pA[5]),  pkt(pA[6],  pA[7])  };
            u32x4 B1w = { pkt(pA[8],  pA[9]),  pkt(pA[10], pA[11]),
                          pkt(pA[12], pA[13]), pkt(pA[14], pA[15]) };
            bf16x8 PB0 = __builtin_bit_cast(bf16x8, B0w);
            bf16x8 PB1 = __builtin_bit_cast(bf16x8, B1w);
            __builtin_amdgcn_s_setprio(1);
            OA0 = __builtin_amdgcn_mfma_f32_32x32x16_bf16(vf0, PB0, OA0, 0, 0, 0);
            OA0 = __builtin_amdgcn_mfma_f32_32x32x16_bf16(vf1, PB1, OA0, 0, 0, 0);
            OA1 = __builtin_amdgcn_mfma_f32_32x32x16_bf16(vf2, PB0, OA1, 0, 0, 0);
            OA1 = __builtin_amdgcn_mfma_f32_32x32x16_bf16(vf3, PB1, OA1, 0, 0, 0);
            __builtin_amdgcn_s_setprio(0);
        }
        {
            float ps = 0.f;
            #pragma unroll
            for (int r = 0; r < 16; ++r) {
                pB[r] = __builtin_amdgcn_exp2f(pB[r] - mB);
                ps += pB[r];
            }
            lB += ps;
            u32x4 B0w = { pkt(pB[0],  pB[1]),  pkt(pB[2],  pB[3]),
                          pkt(pB[4],  pB[5]),  pkt(pB[6],  pB[7])  };
            u32x4 B1w = { pkt(pB[8],  pB[9]),  pkt(pB[10], pB[11]),
                          pkt(pB[12], pB[13]), pkt(pB[14], pB[15]) };
            bf16x8 PB0 = __builtin_bit_cast(bf16x8, B0w);
            bf16x8 PB1 = __builtin_bit_cast(bf16x8, B1w);
            __builtin_amdgcn_s_setprio(1);
            OB0 = __builtin_amdgcn_mfma_f32_32x32x16_bf16(vf0, PB0, OB0, 0, 0, 0);
            OB0 = __builtin_amdgcn_mfma_f32_32x32x16_bf16(vf1, PB1, OB0, 0, 0, 0);
            OB1 = __builtin_amdgcn_mfma_f32_32x32x16_bf16(vf2, PB0, OB1, 0, 0, 0);
            OB1 = __builtin_amdgcn_mfma_f32_32x32x16_bf16(vf3, PB1, OB1, 0, 0, 0);
            __builtin_amdgcn_s_setprio(0);
        }
    };

    bf16x8 kA_[4], kB_[4];
    if (wid < NT) loadK(kA_, wid);
    for (int st = wid; st < NT; st += 8) {
        if (st + 4 < NT) loadK(kB_, st + 4);
        process(kA_, st);
        if (st + 4 >= NT) break;
        if (st + 8 < NT) loadK(kA_, st + 8);
        process(kB_, st + 4);
    }
    lA += __shfl_xor(lA, 32);
    lB += __shfl_xor(lB, 32);

    // ---- merge the 4 wave-partials in LDS (bf16-packed, stride 34 u32) ----
    __shared__ unsigned OSu[4][64 * 34];
    __shared__ float mS[4][64], lS[4][64];
    if (h == 0) {
        mS[wid][c] = mA;      lS[wid][c] = lA;
        mS[wid][32 + c] = mB; lS[wid][32 + c] = lB;
    }
    {
        unsigned* os = &OSu[wid][0];
        const int rbA = c * 34 + 2 * h;
        const int rbB = (32 + c) * 34 + 2 * h;
        #pragma unroll
        for (int j = 0; j < 4; ++j) {
            os[rbA + 4*j]          = pk2(OA0[4*j],   OA0[4*j+1]);
            os[rbA + 4*j + 1]      = pk2(OA0[4*j+2], OA0[4*j+3]);
            os[rbA + 16 + 4*j]     = pk2(OA1[4*j],   OA1[4*j+1]);
            os[rbA + 16 + 4*j + 1] = pk2(OA1[4*j+2], OA1[4*j+3]);
            os[rbB + 4*j]          = pk2(OB0[4*j],   OB0[4*j+1]);
            os[rbB + 4*j + 1]      = pk2(OB0[4*j+2], OB0[4*j+3]);
            os[rbB + 16 + 4*j]     = pk2(OB1[4*j],   OB1[4*j+1]);
            os[rbB + 16 + 4*j + 1] = pk2(OB1[4*j+2], OB1[4*j+3]);
        }
    }
    __syncthreads();

    const int ql = tid & 63, ug = (tid >> 6) * 8;   // 8 u32 = 16 d per thread
    const float M = fmaxf(fmaxf(mS[0][ql], mS[1][ql]), fmaxf(mS[2][ql], mS[3][ql]));
    float acc[16] = {};
    float L = 0.f;
    #pragma unroll
    for (int w2 = 0; w2 < 4; ++w2) {
        const float sc = __builtin_amdgcn_exp2f(mS[w2][ql] - M);
        L += lS[w2][ql] * sc;
        u32x4 pa = *(u32x4*)&OSu[w2][ql * 34 + ug];
        u32x4 pb = *(u32x4*)&OSu[w2][ql * 34 + ug + 4];
        #pragma unroll
        for (int t = 0; t < 4; ++t) {
            acc[2*t]     += __builtin_bit_cast(float, pa[t] << 16) * sc;
            acc[2*t+1]   += __builtin_bit_cast(float, pa[t] & 0xffff0000u) * sc;
            acc[8+2*t]   += __builtin_bit_cast(float, pb[t] << 16) * sc;
            acc[8+2*t+1] += __builtin_bit_cast(float, pb[t] & 0xffff0000u) * sc;
        }
    }
    const float inv = 1.0f / L;
    uint4 ov0, ov1;
    ov0.x = pk2(acc[0]*inv,  acc[1]*inv);
    ov0.y = pk2(acc[2]*inv,  acc[3]*inv);
    ov0.z = pk2(acc[4]*inv,  acc[5]*inv);
    ov0.w = pk2(acc[6]*inv,  acc[7]*inv);
    ov1.x = pk2(acc[8]*inv,  acc[9]*inv);
    ov1.y = pk2(acc[10]*inv, acc[11]*inv);
    ov1.z = pk2(acc[12]*inv, acc[13]*inv);
    ov1.w = pk2(acc[14]*inv, acc[15]*inv);
    unsigned short* orow = ab + ((size_t)(b * T_) + q0 + ql) * HID_ + hh * 64 + ug * 2;
    *(uint4*)orow       = ov0;
    *(uint4*)(orow + 8) = ov1;
}

extern "C" void kernel_launch(void* const* d_in, const int* in_sizes, int n_in,
                              void* d_out, int out_size, void* d_ws, size_t ws_size,
                              hipStream_t stream) {
    const float* x  = (const float*)d_in[0];
    const float* Wq = (const float*)d_in[1];
    const float* Wk = (const float*)d_in[2];
    const float* Wv = (const float*)d_in[3];
    const float* Wo = (const float*)d_in[4];
    const float* cs = (const float*)d_in[5];
    const float* sn = (const float*)d_in[6];
    char* wsb = (char*)d_ws;
    unsigned short* xb  = (unsigned short*)(wsb);                  // 8 MB
    unsigned short* wqb = (unsigned short*)(wsb + (8u  << 20));    // 2 MB each
    unsigned short* wkb = (unsigned short*)(wsb + (10u << 20));
    unsigned short* wvb = (unsigned short*)(wsb + (12u << 20));
    unsigned short* wob = (unsigned short*)(wsb + (14u << 20));
    unsigned short* qb  = (unsigned short*)(wsb + (16u << 20));
    unsigned short* kb  = (unsigned short*)(wsb + (24u << 20));
    unsigned short* vtb = (unsigned short*)(wsb + (32u << 20));
    unsigned short* ab  = (unsigned short*)(wsb + (40u << 20));

    cast_all<<<4096, 256, 0, stream>>>(x, Wq, Wk, Wv, Wo, xb, wqb, wkb, wvb, wob);

    gemm_k<0><<<dim3(M_/128, 3072/128), 256, 0, stream>>>(
        xb, wqb, wkb, wvb, cs, sn, qb, kb, vtb, nullptr);
    attn15<<<1024, 256, 0, stream>>>(qb, kb, vtb, ab);
    gemm_k<1><<<dim3(M_/128, HID_/128), 256, 0, stream>>>(
        ab, wob, nullptr, nullptr, nullptr, nullptr,
        nullptr, nullptr, nullptr, (float*)d_out);
}

// Round 18
// 116.305 us; speedup vs baseline: 1.2352x; 1.0183x over previous
//
#include <hip/hip_runtime.h>
#include <hip/hip_bf16.h>

#define B_   2
#define T_   2048
#define HID_ 1024
#define NH_  16
#define HD_  64
#define K_   1024
#define M_   (B_*T_)

typedef __attribute__((ext_vector_type(8)))  short bf16x8;
typedef __attribute__((ext_vector_type(4)))  float f32x4;
typedef __attribute__((ext_vector_type(16))) float f32x16;
typedef __attribute__((ext_vector_type(4)))  unsigned int u32x4;
typedef __attribute__((ext_vector_type(2)))  unsigned int u32x2;

#define LOG2E 1.44269504088896340736f

__device__ inline unsigned short f2bf(float f) {
    __hip_bfloat16 h = __float2bfloat16(f);
    return __builtin_bit_cast(unsigned short, h);
}
__device__ inline unsigned int pk2(float a, float b) {
    return (unsigned int)f2bf(a) | ((unsigned int)f2bf(b) << 16);
}
// truncation pack: (a>>16) | (b & 0xffff0000) in ONE v_perm_b32
__device__ inline unsigned int pkt(float a, float b) {
    return __builtin_amdgcn_perm(__builtin_bit_cast(unsigned, a),
                                 __builtin_bit_cast(unsigned, b), 0x03020706u);
}
__device__ inline bf16x8 cvt8(float4 a, float4 b) {
    bf16x8 r;
    r[0]=(short)f2bf(a.x); r[1]=(short)f2bf(a.y); r[2]=(short)f2bf(a.z); r[3]=(short)f2bf(a.w);
    r[4]=(short)f2bf(b.x); r[5]=(short)f2bf(b.y); r[6]=(short)f2bf(b.z); r[7]=(short)f2bf(b.w);
    return r;
}

// ---------------- fp32 -> bf16 cast, single launch (x + 4 weights) ----------------
__global__ __launch_bounds__(256)
void cast_all(const float* __restrict__ x,
              const float* __restrict__ W0, const float* __restrict__ W1,
              const float* __restrict__ W2, const float* __restrict__ W3,
              unsigned short* __restrict__ xo,
              unsigned short* __restrict__ o0, unsigned short* __restrict__ o1,
              unsigned short* __restrict__ o2, unsigned short* __restrict__ o3) {
    const int blk = blockIdx.x;
    const float* in;
    unsigned short* out;
    int i;
    if (blk < 2048) {
        in = x; out = xo; i = blk * 256 + threadIdx.x;
    } else {
        const int wb = blk - 2048, sec = wb >> 9;
        in  = (sec == 0) ? W0 : (sec == 1) ? W1 : (sec == 2) ? W2 : W3;
        out = (sec == 0) ? o0 : (sec == 1) ? o1 : (sec == 2) ? o2 : o3;
        i = (wb & 511) * 256 + threadIdx.x;
    }
    float4 a = ((const float4*)in)[2*i], b = ((const float4*)in)[2*i + 1];
    ((bf16x8*)out)[i] = cvt8(a, b);
}

// ---------------- bf16 GEMM-NT (proven; kappa-permuted V epilogue) ----------------
template<int TYPE>
__global__ __launch_bounds__(256)
void gemm_k(const unsigned short* __restrict__ A, const unsigned short* __restrict__ W0,
            const unsigned short* __restrict__ W1, const unsigned short* __restrict__ W2,
            const float* __restrict__ cs, const float* __restrict__ sn,
            unsigned short* __restrict__ qb, unsigned short* __restrict__ kb,
            unsigned short* __restrict__ vtb, float* __restrict__ fout) {
    __shared__ unsigned short As[128*64];
    __shared__ unsigned short Bs[128*64];
    const int tid = threadIdx.x;
    const int w = tid >> 6, lane = tid & 63;
    const int u = lane >> 4, c = lane & 15;
    const int bm = blockIdx.x * 128, bn = blockIdx.y * 128;
    const int wm = (w & 1) * 64, wn = (w >> 1) * 64;
    const int srow = tid >> 3, scol = (tid & 7) << 3;

    const unsigned short* Wsec;
    int wrowbase;
    if constexpr (TYPE == 0) {
        const int sec = bn >> 10;
        Wsec = (sec == 0) ? W0 : ((sec == 1) ? W1 : W2);
        wrowbase = bn & 1023;
    } else {
        Wsec = W0;
        wrowbase = bn;
    }
    const unsigned short* Wp = Wsec + (size_t)(wrowbase + srow) * K_ + scol;
    const unsigned short* Ap = A + (size_t)(bm + srow) * K_ + scol;

    f32x4 acc[4][4] = {};
    bf16x8 ra[4], rb[4];

    auto loadin = [&](int k0) {
        #pragma unroll
        for (int i = 0; i < 4; ++i) {
            ra[i] = *(const bf16x8*)(Ap + (size_t)i * 32 * K_ + k0);
            rb[i] = *(const bf16x8*)(Wp + (size_t)i * 32 * K_ + k0);
        }
    };
    loadin(0);

    for (int k0 = 0; k0 < K_; k0 += 64) {
        __syncthreads();
        #pragma unroll
        for (int i = 0; i < 4; ++i) {
            const int row = i * 32 + srow;
            const int sc = (scol * 2) ^ ((row & 7) << 4);
            *(bf16x8*)((char*)As + row * 128 + sc) = ra[i];
            *(bf16x8*)((char*)Bs + row * 128 + sc) = rb[i];
        }
        __syncthreads();
        if (k0 < K_ - 64) loadin(k0 + 64);
        #pragma unroll
        for (int kk = 0; kk < 2; ++kk) {
            bf16x8 af[4], bfr[4];
            #pragma unroll
            for (int mi = 0; mi < 4; ++mi) {
                const int row = wm + mi * 16 + c;
                const int sc = (kk * 64 + u * 16) ^ ((row & 7) << 4);
                af[mi] = *(const bf16x8*)((char*)As + row * 128 + sc);
            }
            #pragma unroll
            for (int ni = 0; ni < 4; ++ni) {
                const int row = wn + ni * 16 + c;
                const int sc = (kk * 64 + u * 16) ^ ((row & 7) << 4);
                bfr[ni] = *(const bf16x8*)((char*)Bs + row * 128 + sc);
            }
            #pragma unroll
            for (int mi = 0; mi < 4; ++mi)
                #pragma unroll
                for (int ni = 0; ni < 4; ++ni)
                    acc[mi][ni] = __builtin_amdgcn_mfma_f32_16x16x32_bf16(
                        af[mi], bfr[ni], acc[mi][ni], 0, 0, 0);
        }
    }

    if constexpr (TYPE == 1) {
        #pragma unroll
        for (int mi = 0; mi < 4; ++mi)
            #pragma unroll
            for (int ni = 0; ni < 4; ++ni)
                #pragma unroll
                for (int r = 0; r < 4; ++r)
                    fout[(size_t)(bm + wm + 16*mi + 4*u + r) * HID_ + (bn + wn + 16*ni + c)] =
                        acc[mi][ni][r];
    } else {
        const int sec = bn >> 10;
        const int h = ((bn + wn) & 1023) >> 6;
        if (sec == 2) {
            #pragma unroll
            for (int mi = 0; mi < 4; ++mi)
                #pragma unroll
                for (int r = 0; r < 4; ++r) {
                    const int mg = bm + wm + 16*mi + 4*u + r;
                    const int bb = mg >> 11, t = mg & 2047;
                    const int tk = (t & ~12) | ((t & 4) << 1) | ((t & 8) >> 1);  // kappa
                    #pragma unroll
                    for (int ni = 0; ni < 4; ++ni)
                        vtb[((size_t)(bb*16 + h) * 64 + 16*ni + c) * 2048 + tk] =
                            f2bf(acc[mi][ni][r]);
                }
        } else {
            unsigned short* ob = sec ? kb : qb;
            const float qsc = sec ? 1.0f : (0.125f * LOG2E);   // q in log2 domain
            #pragma unroll
            for (int mi = 0; mi < 4; ++mi)
                #pragma unroll
                for (int r = 0; r < 4; ++r) {
                    const int mg = bm + wm + 16*mi + 4*u + r;
                    const int bb = mg >> 11, t = mg & 2047;
                    const size_t base = ((size_t)(bb*16 + h) * 2048 + t) * 64;
                    #pragma unroll
                    for (int ni = 0; ni < 2; ++ni) {
                        const int dlo = 16*ni + c;
                        const float cv = cs[t*64 + dlo], sv = sn[t*64 + dlo];
                        const float Aa = acc[mi][ni][r], Bb = acc[mi][ni+2][r];
                        ob[base + dlo]      = f2bf((Aa*cv - Bb*sv) * qsc);
                        ob[base + dlo + 32] = f2bf((Bb*cv + Aa*sv) * qsc);
                    }
                }
        }
    }
}

// ---------------- attn16: single-K-buffer pipeline (target <=168 VGPR) ----------------
// attn15's math verbatim. K prefetch for st+4 overwrites the SAME kf buffer right
// after QK^T(st)'s last read (WAR, compiler-tracked) — load flies over softmax+PV
// (~600cy), same cover as the double buffer at half the registers. No occupancy
// cap (R7/R16 lesson); if allocation lands <=168 we get 3 waves/SIMD for free.
__global__ __launch_bounds__(256)
void attn16(const unsigned short* __restrict__ q, const unsigned short* __restrict__ k,
            const unsigned short* __restrict__ vt, unsigned short* __restrict__ ab) {
    const int raw = blockIdx.x;                          // 1024 blocks
    const int bh     = (raw & 7) + 8 * ((raw >> 3) & 3); // same-bh -> same XCD
    const int qchunk = 31 - (raw >> 5);                  // heavy blocks first
    const int tid = threadIdx.x;
    const int wid = tid >> 6, lane = tid & 63;
    const int h = lane >> 5, c = lane & 31;
    const int b = bh >> 4, hh = bh & 15;
    const int q0 = qchunk * 64;
    const int qgcA = q0 + c, qgcB = q0 + 32 + c;
    const int stAd = 2 * qchunk;                         // tile A diag subtile
    const int NT   = 2 * qchunk + 2;                     // KV subtiles (tile B diag = NT-1)
    const unsigned short* qp = q  + (size_t)bh * (T_*64);
    const unsigned short* kp = k  + (size_t)bh * (T_*64);
    const unsigned short* vp = vt + (size_t)bh * (64*T_);

    const int kloff  = c * 64 + 8 * h;
    const int vloff0 = c * 2048 + 8 * h;
    const int vloff1 = vloff0 + 32 * 2048;

    bf16x8 qfA[4], qfB[4];
    {
        const unsigned short* qrowA = qp + (q0 + c) * 64 + 8 * h;
        const unsigned short* qrowB = qrowA + 32 * 64;
        #pragma unroll
        for (int s = 0; s < 4; ++s) {
            qfA[s] = *(const bf16x8*)(qrowA + s * 16);
            qfB[s] = *(const bf16x8*)(qrowB + s * 16);
        }
    }

    f32x16 OA0 = {}, OA1 = {}, OB0 = {}, OB1 = {};
    float mA = -1e30f, lA = 0.f, mB = -1e30f, lB = 0.f;

    auto loadK = [&](bf16x8 (&kf)[4], int st) {
        const unsigned short* kst = kp + (st << 11);
        #pragma unroll
        for (int s = 0; s < 4; ++s)
            kf[s] = *(const bf16x8*)(kst + kloff + s * 16);
    };

    auto process = [&](bf16x8 (&kf)[4], int st) {
        const int kvs = st << 5;
        // V loads issue NOW; consumed after QK^T + softmax (~400cy of cover)
        const unsigned short* vst = vp + (st << 5);
        bf16x8 vf0 = *(const bf16x8*)(vst + vloff0);
        bf16x8 vf1 = *(const bf16x8*)(vst + vloff0 + 16);
        bf16x8 vf2 = *(const bf16x8*)(vst + vloff1);
        bf16x8 vf3 = *(const bf16x8*)(vst + vloff1 + 16);
        const bool doA = (st <= stAd);                   // uniform
        float pA[16], pB[16];
        float mxA = -1e30f, mxB;
        if (doA) {
            __builtin_amdgcn_s_setprio(1);
            f32x16 sa = {};
            #pragma unroll
            for (int s = 0; s < 4; ++s)
                sa = __builtin_amdgcn_mfma_f32_32x32x16_bf16(kf[s], qfA[s], sa, 0, 0, 0);
            __builtin_amdgcn_s_setprio(0);
            #pragma unroll
            for (int r = 0; r < 16; ++r) pA[r] = sa[r];
            if (st == stAd) {
                #pragma unroll
                for (int r = 0; r < 16; ++r) {
                    const int kk = kvs + (r & 3) + 8 * (r >> 2) + 4 * h;
                    if (kk > qgcA) pA[r] = -1e30f;
                }
            }
            const float a0 = fmaxf(fmaxf(pA[0],  pA[1]),  pA[2]);
            const float a1 = fmaxf(fmaxf(pA[3],  pA[4]),  pA[5]);
            const float a2 = fmaxf(fmaxf(pA[6],  pA[7]),  pA[8]);
            const float a3 = fmaxf(fmaxf(pA[9],  pA[10]), pA[11]);
            const float a4 = fmaxf(fmaxf(pA[12], pA[13]), pA[14]);
            mxA = fmaxf(fmaxf(fmaxf(a0, a1), fmaxf(a2, a3)), fmaxf(a4, pA[15]));
        }
        {
            __builtin_amdgcn_s_setprio(1);
            f32x16 sa = {};
            #pragma unroll
            for (int s = 0; s < 4; ++s)
                sa = __builtin_amdgcn_mfma_f32_32x32x16_bf16(kf[s], qfB[s], sa, 0, 0, 0);
            __builtin_amdgcn_s_setprio(0);
            #pragma unroll
            for (int r = 0; r < 16; ++r) pB[r] = sa[r];
            if (st == NT - 1) {
                #pragma unroll
                for (int r = 0; r < 16; ++r) {
                    const int kk = kvs + (r & 3) + 8 * (r >> 2) + 4 * h;
                    if (kk > qgcB) pB[r] = -1e30f;
                }
            }
            const float a0 = fmaxf(fmaxf(pB[0],  pB[1]),  pB[2]);
            const float a1 = fmaxf(fmaxf(pB[3],  pB[4]),  pB[5]);
            const float a2 = fmaxf(fmaxf(pB[6],  pB[7]),  pB[8]);
            const float a3 = fmaxf(fmaxf(pB[9],  pB[10]), pB[11]);
            const float a4 = fmaxf(fmaxf(pB[12], pB[13]), pB[14]);
            mxB = fmaxf(fmaxf(fmaxf(a0, a1), fmaxf(a2, a3)), fmaxf(a4, pB[15]));
        }
        // kf's last read was the B QK^T — prefetch st+4 into the SAME buffer now;
        // the load is covered by the softmax+PV below (~600cy).
        if (st + 4 < NT) loadK(kf, st + 4);
        if (!__all(fmaxf(mxA - mA, mxB - mB) <= 8.0f)) {
            if (doA) {
                const float fx = fmaxf(mxA, __shfl_xor(mxA, 32));
                const float mn = fmaxf(mA, fx);
                const float f = __builtin_amdgcn_exp2f(mA - mn);
                mA = mn; lA *= f;
                #pragma unroll
                for (int r = 0; r < 16; ++r) { OA0[r] *= f; OA1[r] *= f; }
            }
            {
                const float fx = fmaxf(mxB, __shfl_xor(mxB, 32));
                const float mn = fmaxf(mB, fx);
                const float f = __builtin_amdgcn_exp2f(mB - mn);
                mB = mn; lB *= f;
                #pragma unroll
                for (int r = 0; r < 16; ++r) { OB0[r] *= f; OB1[r] *= f; }
            }
        }
        if (doA) {
            float ps = 0.f;
            #pragma unroll
            for (int r = 0; r < 16; ++r) {
                pA[r] = __builtin_amdgcn_exp2f(pA[r] - mA);
                ps += pA[r];
            }
            lA += ps;
            u32x4 B0w = { pkt(pA[0],  pA[1]),  pkt(pA[2],  pA[3]),
                          pkt(pA[4],  pA[5]),  pkt(pA[6],  pA[7])  };
            u32x4 B1w = { pkt(pA[8],  pA[9]),  pkt(pA[10], pA[11]),
                          pkt(pA[12], pA[13]), pkt(pA[14], pA[15]) };
            bf16x8 PB0 = __builtin_bit_cast(bf16x8, B0w);
            bf16x8 PB1 = __builtin_bit_cast(bf16x8, B1w);
            __builtin_amdgcn_s_setprio(1);
            OA0 = __builtin_amdgcn_mfma_f32_32x32x16_bf16(vf0, PB0, OA0, 0, 0, 0);
            OA0 = __builtin_amdgcn_mfma_f32_32x32x16_bf16(vf1, PB1, OA0, 0, 0, 0);
            OA1 = __builtin_amdgcn_mfma_f32_32x32x16_bf16(vf2, PB0, OA1, 0, 0, 0);
            OA1 = __builtin_amdgcn_mfma_f32_32x32x16_bf16(vf3, PB1, OA1, 0, 0, 0);
            __builtin_amdgcn_s_setprio(0);
        }
        {
            float ps = 0.f;
            #pragma unroll
            for (int r = 0; r < 16; ++r) {
                pB[r] = __builtin_amdgcn_exp2f(pB[r] - mB);
                ps += pB[r];
            }
            lB += ps;
            u32x4 B0w = { pkt(pB[0],  pB[1]),  pkt(pB[2],  pB[3]),
                          pkt(pB[4],  pB[5]),  pkt(pB[6],  pB[7])  };
            u32x4 B1w = { pkt(pB[8],  pB[9]),  pkt(pB[10], pB[11]),
                          pkt(pB[12], pB[13]), pkt(pB[14], pB[15]) };
            bf16x8 PB0 = __builtin_bit_cast(bf16x8, B0w);
            bf16x8 PB1 = __builtin_bit_cast(bf16x8, B1w);
            __builtin_amdgcn_s_setprio(1);
            OB0 = __builtin_amdgcn_mfma_f32_32x32x16_bf16(vf0, PB0, OB0, 0, 0, 0);
            OB0 = __builtin_amdgcn_mfma_f32_32x32x16_bf16(vf1, PB1, OB0, 0, 0, 0);
            OB1 = __builtin_amdgcn_mfma_f32_32x32x16_bf16(vf2, PB0, OB1, 0, 0, 0);
            OB1 = __builtin_amdgcn_mfma_f32_32x32x16_bf16(vf3, PB1, OB1, 0, 0, 0);
            __builtin_amdgcn_s_setprio(0);
        }
    };

    bf16x8 kf_[4];
    if (wid < NT) {
        loadK(kf_, wid);
        for (int st = wid; st < NT; st += 4)
            process(kf_, st);
    }
    lA += __shfl_xor(lA, 32);
    lB += __shfl_xor(lB, 32);

    // ---- merge the 4 wave-partials in LDS (bf16-packed, stride 34 u32) ----
    __shared__ unsigned OSu[4][64 * 34];
    __shared__ float mS[4][64], lS[4][64];
    if (h == 0) {
        mS[wid][c] = mA;      lS[wid][c] = lA;
        mS[wid][32 + c] = mB; lS[wid][32 + c] = lB;
    }
    {
        unsigned* os = &OSu[wid][0];
        const int rbA = c * 34 + 2 * h;
        const int rbB = (32 + c) * 34 + 2 * h;
        #pragma unroll
        for (int j = 0; j < 4; ++j) {
            os[rbA + 4*j]          = pk2(OA0[4*j],   OA0[4*j+1]);
            os[rbA + 4*j + 1]      = pk2(OA0[4*j+2], OA0[4*j+3]);
            os[rbA + 16 + 4*j]     = pk2(OA1[4*j],   OA1[4*j+1]);
            os[rbA + 16 + 4*j + 1] = pk2(OA1[4*j+2], OA1[4*j+3]);
            os[rbB + 4*j]          = pk2(OB0[4*j],   OB0[4*j+1]);
            os[rbB + 4*j + 1]      = pk2(OB0[4*j+2], OB0[4*j+3]);
            os[rbB + 16 + 4*j]     = pk2(OB1[4*j],   OB1[4*j+1]);
            os[rbB + 16 + 4*j + 1] = pk2(OB1[4*j+2], OB1[4*j+3]);
        }
    }
    __syncthreads();

    const int ql = tid & 63, ug = (tid >> 6) * 8;   // 8 u32 = 16 d per thread
    const float M = fmaxf(fmaxf(mS[0][ql], mS[1][ql]), fmaxf(mS[2][ql], mS[3][ql]));
    float acc[16] = {};
    float L = 0.f;
    #pragma unroll
    for (int w2 = 0; w2 < 4; ++w2) {
        const float sc = __builtin_amdgcn_exp2f(mS[w2][ql] - M);
        L += lS[w2][ql] * sc;
        u32x4 pa = *(u32x4*)&OSu[w2][ql * 34 + ug];
        u32x4 pb = *(u32x4*)&OSu[w2][ql * 34 + ug + 4];
        #pragma unroll
        for (int t = 0; t < 4; ++t) {
            acc[2*t]     += __builtin_bit_cast(float, pa[t] << 16) * sc;
            acc[2*t+1]   += __builtin_bit_cast(float, pa[t] & 0xffff0000u) * sc;
            acc[8+2*t]   += __builtin_bit_cast(float, pb[t] << 16) * sc;
            acc[8+2*t+1] += __builtin_bit_cast(float, pb[t] & 0xffff0000u) * sc;
        }
    }
    const float inv = 1.0f / L;
    uint4 ov0, ov1;
    ov0.x = pk2(acc[0]*inv,  acc[1]*inv);
    ov0.y = pk2(acc[2]*inv,  acc[3]*inv);
    ov0.z = pk2(acc[4]*inv,  acc[5]*inv);
    ov0.w = pk2(acc[6]*inv,  acc[7]*inv);
    ov1.x = pk2(acc[8]*inv,  acc[9]*inv);
    ov1.y = pk2(acc[10]*inv, acc[11]*inv);
    ov1.z = pk2(acc[12]*inv, acc[13]*inv);
    ov1.w = pk2(acc[14]*inv, acc[15]*inv);
    unsigned short* orow = ab + ((size_t)(b * T_) + q0 + ql) * HID_ + hh * 64 + ug * 2;
    *(uint4*)orow       = ov0;
    *(uint4*)(orow + 8) = ov1;
}

extern "C" void kernel_launch(void* const* d_in, const int* in_sizes, int n_in,
                              void* d_out, int out_size, void* d_ws, size_t ws_size,
                              hipStream_t stream) {
    const float* x  = (const float*)d_in[0];
    const float* Wq = (const float*)d_in[1];
    const float* Wk = (const float*)d_in[2];
    const float* Wv = (const float*)d_in[3];
    const float* Wo = (const float*)d_in[4];
    const float* cs = (const float*)d_in[5];
    const float* sn = (const float*)d_in[6];
    char* wsb = (char*)d_ws;
    unsigned short* xb  = (unsigned short*)(wsb);                  // 8 MB
    unsigned short* wqb = (unsigned short*)(wsb + (8u  << 20));    // 2 MB each
    unsigned short* wkb = (unsigned short*)(wsb + (10u << 20));
    unsigned short* wvb = (unsigned short*)(wsb + (12u << 20));
    unsigned short* wob = (unsigned short*)(wsb + (14u << 20));
    unsigned short* qb  = (unsigned short*)(wsb + (16u << 20));
    unsigned short* kb  = (unsigned short*)(wsb + (24u << 20));
    unsigned short* vtb = (unsigned short*)(wsb + (32u << 20));
    unsigned short* ab  = (unsigned short*)(wsb + (40u << 20));

    cast_all<<<4096, 256, 0, stream>>>(x, Wq, Wk, Wv, Wo, xb, wqb, wkb, wvb, wob);

    gemm_k<0><<<dim3(M_/128, 3072/128), 256, 0, stream>>>(
        xb, wqb, wkb, wvb, cs, sn, qb, kb, vtb, nullptr);
    attn16<<<1024, 256, 0, stream>>>(qb, kb, vtb, ab);
    gemm_k<1><<<dim3(M_/128, HID_/128), 256, 0, stream>>>(
        ab, wob, nullptr, nullptr, nullptr, nullptr,
        nullptr, nullptr, nullptr, (float*)d_out);
}